// Round 3
// baseline (194.248 us; speedup 1.0000x reference)
//
#include <hip/hip_runtime.h>

typedef __attribute__((ext_vector_type(8))) short short8;
typedef __attribute__((ext_vector_type(4))) float floatx4;

#define LDS_STRIDE 136  // halfwords/row = 272 B: 16B-aligned (b128 frag reads, 2-way banks = free)

// PACT integer (q - zp) as exact bf16 bits: |q-zp| <= 256 is exact in bf16, so
// fp32-bit truncation is exact (low 16 bits already zero).
__device__ __forceinline__ unsigned short quant_bf16(float x, float cvn, float cv,
                                                     float scale, float zp) {
    float xc = fminf(fmaxf(x, cvn), cv);
    float q  = rintf(xc * scale + zp);   // RNE, matches jnp.round
    float v  = q - zp;                   // integer in [-256, 256]
    return (unsigned short)(__float_as_uint(v) >> 16);
}

// One fused kernel: per 128x128 C-tile, quantize m1/m2 tiles on the fly into
// LDS (m2 transposed in-register so fragments are k-contiguous), then MFMA.
// No workspace round-trip, no inter-kernel serialization, single dispatch.
__global__ __launch_bounds__(256) void fused_qbmm_kernel(
        const float* __restrict__ m1, const float* __restrict__ m2,
        float* __restrict__ C,
        const float* __restrict__ cv1p, const float* __restrict__ cvn1p,
        const float* __restrict__ cv2p, const float* __restrict__ cvn2p) {
    __shared__ __align__(16) unsigned short As[128 * LDS_STRIDE];  // [s][d] bf16-int m1 tile
    __shared__ __align__(16) unsigned short Bs[128 * LDS_STRIDE];  // [t][d] bf16-int m2^T tile

    const int batch = blockIdx.z;
    const int m0 = blockIdx.y * 128, n0 = blockIdx.x * 128;
    const float* Am = m1 + (size_t)batch * (1024 * 128) + (size_t)m0 * 128;
    const float* Bm = m2 + (size_t)batch * (128 * 1024) + n0;
    float* Cb = C + (size_t)batch * (1024 * 1024);

    const float cv1 = cv1p[0], cvn1 = cvn1p[0];
    const float cv2 = cv2p[0], cvn2 = cvn2p[0];
    const float s1 = 255.0f / (cv1 - cvn1);
    const float zp1 = rintf(-cvn1 * s1);
    const float s2 = 255.0f / (cv2 - cvn2);
    const float zp2 = rintf(-cvn2 * s2);

    const int tid = threadIdx.x;

    // ---- stage A: m1 tile [128 s][128 d] fp32 -> As, same layout ----
    {
        const int col4 = tid & 31, r0 = tid >> 5;
#pragma unroll
        for (int r = 0; r < 16; ++r) {
            const int s = r * 8 + r0;
            floatx4 v = *(const floatx4*)(Am + (size_t)s * 128 + col4 * 4);
            ushort4 o;
            o.x = quant_bf16(v[0], cvn1, cv1, s1, zp1);
            o.y = quant_bf16(v[1], cvn1, cv1, s1, zp1);
            o.z = quant_bf16(v[2], cvn1, cv1, s1, zp1);
            o.w = quant_bf16(v[3], cvn1, cv1, s1, zp1);
            *(ushort4*)&As[s * LDS_STRIDE + col4 * 4] = o;  // 8B write, 2-way banks
        }
    }
    // ---- stage B: m2 tile [128 d][128 t] fp32 -> Bs [t][d] (4x4 in-register transpose) ----
    {
        const int t4 = tid & 31, d0 = tid >> 5;
#pragma unroll
        for (int r = 0; r < 4; ++r) {
            const int d4 = r * 8 + d0;   // 4-row d-chunk 0..31
            floatx4 v[4];
#pragma unroll
            for (int i = 0; i < 4; ++i)
                v[i] = *(const floatx4*)(Bm + (size_t)(d4 * 4 + i) * 1024 + t4 * 4);
#pragma unroll
            for (int j = 0; j < 4; ++j) {
                ushort4 w;
                w.x = quant_bf16(v[0][j], cvn2, cv2, s2, zp2);
                w.y = quant_bf16(v[1][j], cvn2, cv2, s2, zp2);
                w.z = quant_bf16(v[2][j], cvn2, cv2, s2, zp2);
                w.w = quant_bf16(v[3][j], cvn2, cv2, s2, zp2);
                *(ushort4*)&Bs[(t4 * 4 + j) * LDS_STRIDE + d4 * 4] = w;
            }
        }
    }
    __syncthreads();

    // ---- MFMA: 4 waves (2x2), 4x4 16x16x32 tiles/wave, K=128 unrolled ----
    const int lane = tid & 63, w = tid >> 6;
    const int wr = w >> 1, wc = w & 1;
    const int row16 = lane & 15, quad = lane >> 4;

    floatx4 acc[4][4] = {};
    const unsigned short* Abase = &As[(wr * 64 + row16) * LDS_STRIDE + quad * 8];
    const unsigned short* Bbase = &Bs[(wc * 64 + row16) * LDS_STRIDE + quad * 8];

#pragma unroll
    for (int kk = 0; kk < 4; ++kk) {
        short8 a[4], b[4];
#pragma unroll
        for (int i = 0; i < 4; ++i) {
            a[i] = *(const short8*)(Abase + i * 16 * LDS_STRIDE + kk * 32);  // b128
            b[i] = *(const short8*)(Bbase + i * 16 * LDS_STRIDE + kk * 32);  // b128
        }
#pragma unroll
        for (int mi = 0; mi < 4; ++mi)
#pragma unroll
            for (int ni = 0; ni < 4; ++ni)
                // D = (B^T)(A^T) = C^T fragment: lane reg r = C[s=mi*16+row16][t=ni*16+quad*4+r]
                acc[mi][ni] = __builtin_amdgcn_mfma_f32_16x16x32_bf16(
                    b[ni], a[mi], acc[mi][ni], 0, 0, 0);
    }

    // inv = 1/(scale1*scale2) = (cv1-cvn1)*(cv2-cvn2)/255^2
    const float inv = (cv1 - cvn1) * (cv2 - cvn2) * (1.0f / 65025.0f);

#pragma unroll
    for (int mi = 0; mi < 4; ++mi) {
        float* crow = Cb + (size_t)(m0 + wr * 64 + mi * 16 + row16) * 1024 + n0 + wc * 64;
#pragma unroll
        for (int ni = 0; ni < 4; ++ni) {
            floatx4 o = acc[mi][ni] * inv;
            *(floatx4*)(crow + ni * 16 + quad * 4) = o;   // 16B store
        }
    }
}

extern "C" void kernel_launch(void* const* d_in, const int* in_sizes, int n_in,
                              void* d_out, int out_size, void* d_ws, size_t ws_size,
                              hipStream_t stream) {
    const float* m1   = (const float*)d_in[0];
    const float* m2   = (const float*)d_in[1];
    const float* cv1  = (const float*)d_in[2];
    const float* cvn1 = (const float*)d_in[3];
    const float* cv2  = (const float*)d_in[4];
    const float* cvn2 = (const float*)d_in[5];
    float* out = (float*)d_out;

    // Single fused dispatch: 8x8 C-tiles x 32 batches. No workspace needed.
    fused_qbmm_kernel<<<dim3(8, 8, 32), 256, 0, stream>>>(m1, m2, out,
                                                          cv1, cvn1, cv2, cvn2);
}